// Round 1
// baseline (154.887 us; speedup 1.0000x reference)
//
#include <hip/hip_runtime.h>
#include <hip/hip_bf16.h>

typedef float f4vec  __attribute__((ext_vector_type(4)));
typedef float f16vec __attribute__((ext_vector_type(16)));
typedef short s8vec  __attribute__((ext_vector_type(8)));

#define B_DIM 64
#define N_DIM 64
#define D_DIM 9216
#define SPLIT 8
#define CHUNK 1152   // D_DIM / SPLIT
#define BK 64

// ws layout (bytes):
//   Spart    @ 0        : 64*8*4096*4 = 8388608   (per-split Gram partials)
//   meanPart @ 8388608   : 64*8*64*4  = 131072
//   meanOut  @ 8519680   : 64*64*4    = 16384
//   Mb(bf16) @ 8536064   : 64*4096*2  = 524288    (M = inv_L - I, row-major)
// total 9060352 bytes

__device__ __forceinline__ short f2bf(float f) {
  union { __hip_bfloat16 h; short s; } u;
  u.h = __float2bfloat16(f);
  return u.s;
}

// Swizzled LDS tile: element (r, c) of a 64x64 fp32 tile lives at
//   r*64 + (((c>>2) ^ (r&15)) << 2) + (c&3)
// -> b128 staging writes, contiguous-row frag reads, and strided-column
//    reads are all uniformly bank-spread.

// ---------------- Kernel 1: partial Gram + row-sum partials ----------------
__global__ __launch_bounds__(256) void k_cov_partial(
    const float* __restrict__ x, float* __restrict__ Spart,
    float* __restrict__ meanPart) {
  const int s = blockIdx.x, b = blockIdx.y;
  const int t = threadIdx.x;
  const int lane = t & 63, w = t >> 6;
  const int wr = w >> 1, wc = w & 1;
  const int hi = lane >> 5;

  __shared__ float T[64 * 64];

  const float* xb = x + (size_t)b * N_DIM * D_DIM + (size_t)s * CHUNK;
  const int jrow = t >> 2, q = t & 3;

  f16vec acc;
#pragma unroll
  for (int r = 0; r < 16; ++r) acc[r] = 0.0f;
  float msum = 0.0f;

  const int r_a = 32 * wr + (lane & 31);
  const int r_b = 32 * wc + (lane & 31);

  for (int step = 0; step < CHUNK / BK; ++step) {
    const int d0 = step * BK;
    __syncthreads();
#pragma unroll
    for (int i = 0; i < 4; ++i) {
      const int f = i * 4 + q;  // float4 index within the row (0..15)
      f4vec v = *reinterpret_cast<const f4vec*>(
          xb + (size_t)jrow * D_DIM + d0 + f * 4);
      msum += v.x + v.y + v.z + v.w;
      *reinterpret_cast<f4vec*>(&T[jrow * 64 + ((f ^ (jrow & 15)) << 2)]) = v;
    }
    __syncthreads();
#pragma unroll
    for (int ks = 0; ks < 4; ++ks) {
      const int c0 = ks * 4 + hi * 2;  // 16B chunk index of this lane's k0
      f4vec a0 = *reinterpret_cast<const f4vec*>(
          &T[r_a * 64 + ((c0 ^ (r_a & 15)) << 2)]);
      f4vec a1 = *reinterpret_cast<const f4vec*>(
          &T[r_a * 64 + (((c0 + 1) ^ (r_a & 15)) << 2)]);
      f4vec b0 = *reinterpret_cast<const f4vec*>(
          &T[r_b * 64 + ((c0 ^ (r_b & 15)) << 2)]);
      f4vec b1 = *reinterpret_cast<const f4vec*>(
          &T[r_b * 64 + (((c0 + 1) ^ (r_b & 15)) << 2)]);
      s8vec af, bf;
      af[0]=f2bf(a0.x); af[1]=f2bf(a0.y); af[2]=f2bf(a0.z); af[3]=f2bf(a0.w);
      af[4]=f2bf(a1.x); af[5]=f2bf(a1.y); af[6]=f2bf(a1.z); af[7]=f2bf(a1.w);
      bf[0]=f2bf(b0.x); bf[1]=f2bf(b0.y); bf[2]=f2bf(b0.z); bf[3]=f2bf(b0.w);
      bf[4]=f2bf(b1.x); bf[5]=f2bf(b1.y); bf[6]=f2bf(b1.z); bf[7]=f2bf(b1.w);
      acc = __builtin_amdgcn_mfma_f32_32x32x16_bf16(af, bf, acc, 0, 0, 0);
    }
  }

  msum += __shfl_xor(msum, 1);
  msum += __shfl_xor(msum, 2);
  if (q == 0) meanPart[(b * SPLIT + s) * 64 + jrow] = msum;

  float* Sp = Spart + (size_t)(b * SPLIT + s) * 4096;
#pragma unroll
  for (int r = 0; r < 16; ++r) {
    const int i = 32 * wr + (r & 3) + 8 * (r >> 2) + 4 * hi;  // C/D row (m74/m101)
    const int j = 32 * wc + (lane & 31);                       // C/D col
    Sp[i * 64 + j] = acc[r];
  }
}

// ---------------- Kernel 2: reduce -> cov -> cholesky -> inv_L -------------
__global__ __launch_bounds__(256) void k_chol_inv(
    const float* __restrict__ Spart, const float* __restrict__ meanPart,
    float* __restrict__ meanOut, unsigned short* __restrict__ Mb) {
  const int b = blockIdx.x;
  const int t = threadIdx.x;

  __shared__ float A[64 * 65];
  __shared__ float X[64 * 65];
  __shared__ float m[64];
  __shared__ float sc[1];

  if (t < 64) {
    float mm = 0.0f;
    for (int p = 0; p < SPLIT; ++p) mm += meanPart[(b * SPLIT + p) * 64 + t];
    m[t] = mm;
    meanOut[b * 64 + t] = mm * (1.0f / D_DIM);
  }
  __syncthreads();

  for (int e = t; e < 4096; e += 256) {
    float ss = 0.0f;
    for (int p = 0; p < SPLIT; ++p)
      ss += Spart[(size_t)(b * SPLIT + p) * 4096 + e];
    const int i = e >> 6, j = e & 63;
    A[i * 65 + j] = (ss - m[i] * m[j] * (1.0f / D_DIM)) * (1.0f / (D_DIM - 1));
  }
  __syncthreads();

  // Right-looking Cholesky (lower), fp32 in LDS.
  const int ci = t & 63, cg = t >> 6;
  for (int k = 0; k < 64; ++k) {
    if (t == 0) {
      float dv = sqrtf(A[k * 65 + k]);
      A[k * 65 + k] = dv;
      sc[0] = 1.0f / dv;
    }
    __syncthreads();
    if (cg == 0 && ci > k) A[ci * 65 + k] *= sc[0];
    __syncthreads();
    if (ci > k) {
      const float lik = A[ci * 65 + k];
      for (int j = k + 1 + cg; j <= ci; j += 4)
        A[ci * 65 + j] -= lik * A[j * 65 + k];
    }
    __syncthreads();
  }

  // Forward-substitution inverse: X = inv(L), column-parallel (4 lanes/col).
  for (int e = t; e < 64 * 65; e += 256) X[e] = 0.0f;
  __syncthreads();
  const int c = t >> 2, sl = t & 3;
  if (sl == 0) X[c * 65 + c] = 1.0f / A[c * 65 + c];
  __syncthreads();
  for (int i = 1; i < 64; ++i) {
    float sum = 0.0f;
    if (c < i) {
      for (int j = c + sl; j < i; j += 4) sum += A[i * 65 + j] * X[j * 65 + c];
    }
    sum += __shfl_xor(sum, 1);
    sum += __shfl_xor(sum, 2);
    if (c < i && sl == 0) X[i * 65 + c] = -sum / A[i * 65 + i];
    __syncthreads();
  }

  // M = inv_L - I, bf16 row-major.
  for (int e = t; e < 4096; e += 256) {
    const int i = e >> 6, j = e & 63;
    float v = (i > j) ? X[i * 65 + j] : (i == j ? X[i * 65 + i] - 1.0f : 0.0f);
    Mb[(size_t)b * 4096 + e] = (unsigned short)f2bf(v);
  }
}

// ---------------- Kernel 3: out = xc + M @ xc ------------------------------
__global__ __launch_bounds__(256) void k_whiten(
    const float* __restrict__ x, const float* __restrict__ meanOut,
    const unsigned short* __restrict__ Mb, float* __restrict__ out) {
  const int cb = blockIdx.x, b = blockIdx.y;
  const int t = threadIdx.x;
  const int lane = t & 63, w = t >> 6;
  const int wr = w >> 1, wc = w & 1;
  const int hi = lane >> 5;

  __shared__ float T[64 * 64];

  // A-operand fragments of M for this lane, loaded once per block:
  // row = 32*wr + (lane&31), k0 = ks*16 + hi*8  (8 consecutive bf16 = 16B).
  s8vec mfrag[4];
  {
    const unsigned short* Mrow =
        Mb + ((size_t)b * 64 + 32 * wr + (lane & 31)) * 64;
#pragma unroll
    for (int ks = 0; ks < 4; ++ks) {
      mfrag[ks] = *reinterpret_cast<const s8vec*>(Mrow + ks * 16 + hi * 8);
    }
  }

  const int jrow = t >> 2, q = t & 3;
  const float meanj = meanOut[b * 64 + jrow];
  const float* xb = x + ((size_t)b * 64 + jrow) * D_DIM;
  const int dcol = 32 * wc + (lane & 31);

  for (int c = 0; c < 4; ++c) {
    const int d0 = (cb * 4 + c) * BK;
    __syncthreads();
#pragma unroll
    for (int i = 0; i < 4; ++i) {
      const int f = i * 4 + q;
      f4vec v = *reinterpret_cast<const f4vec*>(xb + d0 + f * 4);
      v.x -= meanj; v.y -= meanj; v.z -= meanj; v.w -= meanj;
      *reinterpret_cast<f4vec*>(&T[jrow * 64 + ((f ^ (jrow & 15)) << 2)]) = v;
    }
    __syncthreads();

    f16vec acc;
#pragma unroll
    for (int r = 0; r < 16; ++r) acc[r] = 0.0f;

#pragma unroll
    for (int ks = 0; ks < 4; ++ks) {
      const int j0 = ks * 16 + hi * 8;
      s8vec bf;
#pragma unroll
      for (int e = 0; e < 8; ++e) {
        const int j = j0 + e;
        float v = T[j * 64 + (((dcol >> 2) ^ (j & 15)) << 2) + (dcol & 3)];
        bf[e] = f2bf(v);
      }
      acc = __builtin_amdgcn_mfma_f32_32x32x16_bf16(mfrag[ks], bf, acc, 0, 0, 0);
    }

#pragma unroll
    for (int r = 0; r < 16; ++r) {
      const int i = 32 * wr + (r & 3) + 8 * (r >> 2) + 4 * hi;
      const float xcv =
          T[i * 64 + (((dcol >> 2) ^ (i & 15)) << 2) + (dcol & 3)];
      out[((size_t)b * 64 + i) * D_DIM + d0 + dcol] = acc[r] + xcv;
    }
  }
}

extern "C" void kernel_launch(void* const* d_in, const int* in_sizes, int n_in,
                              void* d_out, int out_size, void* d_ws,
                              size_t ws_size, hipStream_t stream) {
  const float* x = (const float*)d_in[0];
  float* out = (float*)d_out;
  char* ws = (char*)d_ws;

  float* Spart = (float*)ws;                           // 8 MB
  float* meanPart = (float*)(ws + 8388608);            // 128 KB
  float* meanOut = (float*)(ws + 8519680);             // 16 KB
  unsigned short* Mb = (unsigned short*)(ws + 8536064);// 512 KB

  k_cov_partial<<<dim3(SPLIT, B_DIM), 256, 0, stream>>>(x, Spart, meanPart);
  k_chol_inv<<<dim3(B_DIM), 256, 0, stream>>>(Spart, meanPart, meanOut, Mb);
  k_whiten<<<dim3(D_DIM / (4 * BK), B_DIM), 256, 0, stream>>>(x, meanOut, Mb,
                                                              out);
}